// Round 1
// baseline (2662.514 us; speedup 1.0000x reference)
//
#include <hip/hip_runtime.h>

#define NN 100000
#define NE 1600000
#define HD 128
#define IND 20
#define LNEPS 1e-5f
#define NLIST 100128   // 3129 blocks * 32
#define CHUNK 25000
#define YPAD 25024     // 782*32

// ---------------- setup kernels ----------------

__global__ void k_init(int* cnt, int* fill_n, int* misc, unsigned* nodelist,
                       float* out, const float* reg_b) {
    int i = blockIdx.x * blockDim.x + threadIdx.x;
    int st = gridDim.x * blockDim.x;
    for (int k = i; k < NN; k += st) { cnt[k] = 0; fill_n[k] = 0; }
    for (int k = i; k < NLIST; k += st) nodelist[k] = 0xFFFFFFFFu;
    if (i < 16) misc[i] = 0;
    if (i == 0) out[0] = reg_b[0];
}

__global__ void k_count(const int* ei, const int* nt, int* cnt, int* misc) {
    int i = blockIdx.x * blockDim.x + threadIdx.x;
    int st = gridDim.x * blockDim.x;
    for (int e = i; e < NE; e += st) atomicAdd(&cnt[ei[NE + e]], 1);
    for (int n = i; n < NN; n += st) atomicAdd(&misc[nt[n]], 1);
}

__global__ void k_alloc(const int* cnt, int* off, float* inv_deg, int* misc) {
    int i = blockIdx.x * blockDim.x + threadIdx.x;
    int st = gridDim.x * blockDim.x;
    for (int n = i; n < NN; n += st) {
        int c = cnt[n];
        off[n] = atomicAdd(&misc[12], c);
        inv_deg[n] = 1.0f / (float)(c > 0 ? c : 1);
    }
    if (i < 4) misc[4 + i] = atomicAdd(&misc[13], (misc[i] + 31) & ~31);
}

__global__ void k_fill(const int* ei, const int* et, const int* nt,
                       const int* off, int* fill_n, int* misc,
                       unsigned* packed, unsigned* nodelist) {
    int i = blockIdx.x * blockDim.x + threadIdx.x;
    int st = gridDim.x * blockDim.x;
    for (int e = i; e < NE; e += st) {
        int d = ei[NE + e];
        int p = off[d] + atomicAdd(&fill_n[d], 1);
        packed[p] = (unsigned)ei[e] | ((unsigned)et[e] << 17);
    }
    for (int n = i; n < NN; n += st) {
        int t = nt[n];
        int p = misc[4 + t] + atomicAdd(&misc[8 + t], 1);
        nodelist[p] = (unsigned)n | ((unsigned)t << 17);
    }
}

__global__ void k_wcat(const float* rel_W, const float* lin_W, float* Wcat) {
    int i = blockIdx.x * blockDim.x + threadIdx.x;
    int st = gridDim.x * blockDim.x;
    for (int idx = i; idx < 2 * 512 * 128; idx += st) {
        int l = idx >> 16;
        int rem = idx & 65535;
        int k = rem >> 7, j = rem & 127;
        float v;
        if (k < 384) v = rel_W[((l * 3 + (k >> 7)) * HD + (k & 127)) * HD + j];
        else         v = lin_W[(l * HD + (k - 384)) * HD + j];
        Wcat[idx] = v;
    }
}

// ---------------- encoder ----------------
// block = 256 threads, 32 same-type nodes (type-bucketed, 32-padded node list)

#define FMA16(A, v0, v1, v2, v3, w)                                       \
    A[0] += v0.x * w; A[1] += v0.y * w; A[2] += v0.z * w; A[3] += v0.w * w; \
    A[4] += v1.x * w; A[5] += v1.y * w; A[6] += v1.z * w; A[7] += v1.w * w; \
    A[8] += v2.x * w; A[9] += v2.y * w; A[10] += v2.z * w; A[11] += v2.w * w; \
    A[12] += v3.x * w; A[13] += v3.y * w; A[14] += v3.z * w; A[15] += v3.w * w;

__global__ __launch_bounds__(256) void k_enc(
        const unsigned* nodelist, const int* z, const float* sd, const float* df,
        const float* cond, const float* mult, const float* z_embed,
        const float* W1, const float* b1, const float* W2, const float* b2,
        float* xout) {
    __shared__ float raw[32][20];
    __shared__ float h1[128][36];
    __shared__ unsigned ent[32];
    int tid = threadIdx.x;
    int base = blockIdx.x * 32;
    if (tid < 32) ent[tid] = nodelist[base + tid];
    __syncthreads();
    if (ent[0] == 0xFFFFFFFFu) return;  // all-pad block (uniform)
    int type = (int)(ent[0] >> 17);

    for (int idx = tid; idx < 32 * 20; idx += 256) {
        int nl = idx / 20, f = idx - nl * 20;
        unsigned e = ent[nl];
        float v = 0.f;
        if (e != 0xFFFFFFFFu) {
            int node = (int)(e & 0x1FFFF);
            if (f < 16)      v = z_embed[z[node] * 16 + f];
            else if (f == 16) v = sd[node];
            else if (f == 17) v = df[node];
            else if (f == 18) v = cond[node];
            else              v = mult[node];
        }
        raw[nl][f] = v;
    }
    __syncthreads();

    int j = tid & 127, n0 = (tid >> 7) * 16;
    const float* W1t = W1 + type * IND * HD;
    const float* W2t = W2 + type * HD * HD;

    float acc[16];
#pragma unroll
    for (int i = 0; i < 16; i++) acc[i] = 0.f;
    for (int k = 0; k < IND; k++) {
        float w = W1t[k * HD + j];
#pragma unroll
        for (int i = 0; i < 16; i++) acc[i] += raw[n0 + i][k] * w;
    }
    float bb = b1[type * HD + j];
#pragma unroll
    for (int i = 0; i < 16; i++) h1[j][n0 + i] = fmaxf(acc[i] + bb, 0.f);
    __syncthreads();

#pragma unroll
    for (int i = 0; i < 16; i++) acc[i] = 0.f;
    for (int k = 0; k < HD; k++) {
        float w = W2t[k * HD + j];
        const float4* hp = (const float4*)&h1[k][n0];
        float4 v0 = hp[0], v1 = hp[1], v2 = hp[2], v3 = hp[3];
        FMA16(acc, v0, v1, v2, v3, w)
    }
    float b2v = b2[type * HD + j];
#pragma unroll
    for (int i = 0; i < 16; i++) {
        unsigned e = ent[n0 + i];
        if (e != 0xFFFFFFFFu) {
            int node = (int)(e & 0x1FFFF);
            xout[node * HD + j] = acc[i] + b2v;
        }
    }
}

// ---------------- phase A: per-dst relation-bucketed aggregation ----------------
// 1 block (128 threads) per node; per-relation sums in registers, no atomics.

__global__ __launch_bounds__(128) void k_agg(
        const float* x, const unsigned* packed, const int* off, const int* cnt,
        const float* inv_deg, float* Y, int node_base) {
    int node = node_base + blockIdx.x;
    int j = threadIdx.x;
    __shared__ unsigned elds[128];
    int o = off[node], c = cnt[node];
    float a0 = 0.f, a1 = 0.f, a2 = 0.f;
    float xv = x[node * HD + j];
    for (int b = 0; b < c; b += 128) {
        __syncthreads();
        int m = c - b; if (m > 128) m = 128;
        if (j < m) elds[j] = packed[o + b + j];
        __syncthreads();
        for (int i = 0; i < m; i++) {
            unsigned e = elds[i];
            int src = (int)(e & 0x1FFFF);
            int rel = (int)(e >> 17);
            float v = x[src * HD + j];
            if (rel == 0) a0 += v; else if (rel == 1) a1 += v; else a2 += v;
        }
    }
    float id = inv_deg[node];
    float* yr = Y + (size_t)blockIdx.x * 512;
    yr[j] = a0 * id; yr[128 + j] = a1 * id; yr[256 + j] = a2 * id; yr[384 + j] = xv;
}

// ---------------- phase B: [32,512]x[512,128] GEMM + bias + LayerNorm ----------------

__global__ __launch_bounds__(256) void k_gemm_ln(
        const float* Y, const float* Wc, const float* lb,
        const float* g, const float* bta, float* xout,
        int node_base, int nvalid) {
    __shared__ float ylds[128][36];
    __shared__ float hlds[32][132];
    __shared__ float stat[32][2];
    int tid = threadIdx.x;
    int nb = blockIdx.x * 32;
    int j = tid & 127, n0 = (tid >> 7) * 16;

    float acc[16];
#pragma unroll
    for (int i = 0; i < 16; i++) acc[i] = 0.f;

    int ln = tid >> 3;           // 0..31  (load-phase node)
    int kb = (tid & 7) * 16;     // 0..112 (load-phase k base)

    for (int kc = 0; kc < 4; kc++) {
        __syncthreads();
        const float* yp = Y + (size_t)(nb + ln) * 512 + kc * 128 + kb;
#pragma unroll
        for (int i = 0; i < 16; i += 4) {
            float4 v = *(const float4*)(yp + i);
            ylds[kb + i][ln] = v.x; ylds[kb + i + 1][ln] = v.y;
            ylds[kb + i + 2][ln] = v.z; ylds[kb + i + 3][ln] = v.w;
        }
        __syncthreads();
        const float* wp = Wc + (kc * 128) * HD + j;
        for (int k = 0; k < 128; k++) {
            float w = wp[k * HD];
            const float4* a = (const float4*)&ylds[k][n0];
            float4 v0 = a[0], v1 = a[1], v2 = a[2], v3 = a[3];
            FMA16(acc, v0, v1, v2, v3, w)
        }
    }

    float bj = lb[j];
#pragma unroll
    for (int i = 0; i < 16; i++) hlds[n0 + i][j] = acc[i] + bj;
    __syncthreads();

    {
        int node = tid >> 3, l8 = tid & 7;
        float s = 0.f, ss = 0.f;
#pragma unroll
        for (int i = 0; i < 16; i++) {
            float v = hlds[node][l8 + 8 * i];
            s += v; ss += v * v;
        }
        for (int d = 4; d >= 1; d >>= 1) {
            s += __shfl_down(s, d, 8);
            ss += __shfl_down(ss, d, 8);
        }
        if (l8 == 0) {
            float mu = s * (1.f / 128.f);
            float var = ss * (1.f / 128.f) - mu * mu;
            stat[node][0] = mu;
            stat[node][1] = rsqrtf(var + LNEPS);
        }
    }
    __syncthreads();

    float gj = g[j], btj = bta[j];
#pragma unroll
    for (int i = 0; i < 16; i++) {
        int nl = nb + n0 + i;
        if (nl < nvalid) {
            float mu = stat[n0 + i][0], rs = stat[n0 + i][1];
            float hv = acc[i] + bj;
            xout[(size_t)(node_base + nl) * HD + j] = (hv - mu) * rs * gj + btj;
        }
    }
}

// ---------------- pooling + regressor ----------------

__global__ __launch_bounds__(256) void k_pool(const float* x, const float* regW, float* out) {
    int tid = threadIdx.x;
    int j = tid & 127;
    float s = 0.f;
    int node = blockIdx.x * 2 + (tid >> 7);
    for (; node < NN; node += gridDim.x * 2) s += x[(size_t)node * HD + j];
    s *= regW[j];
    __shared__ float red[4];
    for (int d = 32; d >= 1; d >>= 1) s += __shfl_down(s, d, 64);
    if ((tid & 63) == 0) red[tid >> 6] = s;
    __syncthreads();
    if (tid == 0) {
        float t = red[0] + red[1] + red[2] + red[3];
        atomicAdd(out, t * (1.0f / (float)NN));
    }
}

// ---------------- launcher ----------------

extern "C" void kernel_launch(void* const* d_in, const int* in_sizes, int n_in,
                              void* d_out, int out_size, void* d_ws, size_t ws_size,
                              hipStream_t stream) {
    const int*   z       = (const int*)d_in[0];
    const float* sd      = (const float*)d_in[1];
    const float* df      = (const float*)d_in[2];
    const float* cond    = (const float*)d_in[3];
    const float* mult    = (const float*)d_in[4];
    const int*   nt      = (const int*)d_in[5];
    const int*   ei      = (const int*)d_in[6];
    const int*   et      = (const int*)d_in[7];
    const float* z_embed = (const float*)d_in[8];
    const float* enc_W1  = (const float*)d_in[9];
    const float* enc_b1  = (const float*)d_in[10];
    const float* enc_W2  = (const float*)d_in[11];
    const float* enc_b2  = (const float*)d_in[12];
    const float* lin_W   = (const float*)d_in[13];
    const float* lin_b   = (const float*)d_in[14];
    const float* rel_W   = (const float*)d_in[15];
    const float* ln_g    = (const float*)d_in[16];
    const float* ln_b    = (const float*)d_in[17];
    const float* reg_W   = (const float*)d_in[18];
    const float* reg_b   = (const float*)d_in[19];
    float* out = (float*)d_out;

    char* p = (char*)d_ws;
    int* cnt        = (int*)p;      p += (size_t)NN * 4;
    int* off        = (int*)p;      p += (size_t)NN * 4;
    int* fill_n     = (int*)p;      p += (size_t)NN * 4;
    int* misc       = (int*)p;      p += 16 * 4;        // cnt4[4] off4[4] fill4[4] ctr[2] pad
    unsigned* packed   = (unsigned*)p; p += (size_t)NE * 4;
    unsigned* nodelist = (unsigned*)p; p += (size_t)NLIST * 4;
    float* inv_deg  = (float*)p;    p += (size_t)NN * 4;
    float* Wcat     = (float*)p;    p += (size_t)2 * 512 * 128 * 4;
    float* x0       = (float*)p;    p += (size_t)NN * HD * 4;
    float* x1       = (float*)p;    p += (size_t)NN * HD * 4;
    float* Y        = (float*)p;    p += (size_t)YPAD * 512 * 4;

    k_init<<<400, 256, 0, stream>>>(cnt, fill_n, misc, nodelist, out, reg_b);
    k_count<<<2048, 256, 0, stream>>>(ei, nt, cnt, misc);
    k_alloc<<<400, 256, 0, stream>>>(cnt, off, inv_deg, misc);
    k_fill<<<2048, 256, 0, stream>>>(ei, et, nt, off, fill_n, misc, packed, nodelist);
    k_wcat<<<512, 256, 0, stream>>>(rel_W, lin_W, Wcat);
    k_enc<<<3129, 256, 0, stream>>>(nodelist, z, sd, df, cond, mult, z_embed,
                                    enc_W1, enc_b1, enc_W2, enc_b2, x0);

    float* xin = x0; float* xout = x1;
    for (int l = 0; l < 2; l++) {
        for (int c = 0; c < 4; c++) {
            int base = c * CHUNK;
            k_agg<<<CHUNK, 128, 0, stream>>>(xin, packed, off, cnt, inv_deg, Y, base);
            k_gemm_ln<<<782, 256, 0, stream>>>(Y, Wcat + (size_t)l * 512 * 128,
                                               lin_b + l * HD, ln_g + l * HD, ln_b + l * HD,
                                               xout, base, CHUNK);
        }
        float* t = xin; xin = xout; xout = t;
    }
    k_pool<<<256, 256, 0, stream>>>(xin, reg_W, out);
}

// Round 2
// 2618.734 us; speedup vs baseline: 1.0167x; 1.0167x over previous
//
#include <hip/hip_runtime.h>

#define NN 100000
#define NE 1600000
#define HD 128
#define IND 20
#define LNEPS 1e-5f
#define NLIST 100128   // 3129 blocks * 32
#define CHUNK 25000
#define YPAD 25024     // 782*32

// ---------------- setup kernels ----------------

__global__ void k_init(int* cnt, int* fill_n, int* misc, unsigned* nodelist,
                       float* out, const float* reg_b) {
    int i = blockIdx.x * blockDim.x + threadIdx.x;
    int st = gridDim.x * blockDim.x;
    for (int k = i; k < NN; k += st) { cnt[k] = 0; fill_n[k] = 0; }
    for (int k = i; k < NLIST; k += st) nodelist[k] = 0xFFFFFFFFu;
    if (i < 16) misc[i] = 0;
    if (i == 0) out[0] = reg_b[0];
}

__global__ void k_count(const int* ei, const int* nt, int* cnt, int* misc) {
    int i = blockIdx.x * blockDim.x + threadIdx.x;
    int st = gridDim.x * blockDim.x;
    for (int e = i; e < NE; e += st) atomicAdd(&cnt[ei[NE + e]], 1);
    for (int n = i; n < NN; n += st) atomicAdd(&misc[nt[n]], 1);
}

__global__ void k_alloc(const int* cnt, int* off, float* inv_deg, int* misc) {
    int i = blockIdx.x * blockDim.x + threadIdx.x;
    int st = gridDim.x * blockDim.x;
    for (int n = i; n < NN; n += st) {
        int c = cnt[n];
        off[n] = atomicAdd(&misc[12], c);
        inv_deg[n] = 1.0f / (float)(c > 0 ? c : 1);
    }
    if (i < 4) misc[4 + i] = atomicAdd(&misc[13], (misc[i] + 31) & ~31);
}

__global__ void k_fill(const int* ei, const int* et, const int* nt,
                       const int* off, int* fill_n, int* misc,
                       unsigned* packed, unsigned* nodelist) {
    int i = blockIdx.x * blockDim.x + threadIdx.x;
    int st = gridDim.x * blockDim.x;
    for (int e = i; e < NE; e += st) {
        int d = ei[NE + e];
        int p = off[d] + atomicAdd(&fill_n[d], 1);
        packed[p] = (unsigned)ei[e] | ((unsigned)et[e] << 17);
    }
    for (int n = i; n < NN; n += st) {
        int t = nt[n];
        int p = misc[4 + t] + atomicAdd(&misc[8 + t], 1);
        nodelist[p] = (unsigned)n | ((unsigned)t << 17);
    }
}

__global__ void k_wcat(const float* rel_W, const float* lin_W, float* Wcat) {
    int i = blockIdx.x * blockDim.x + threadIdx.x;
    int st = gridDim.x * blockDim.x;
    for (int idx = i; idx < 2 * 512 * 128; idx += st) {
        int l = idx >> 16;
        int rem = idx & 65535;
        int k = rem >> 7, j = rem & 127;
        float v;
        if (k < 384) v = rel_W[((l * 3 + (k >> 7)) * HD + (k & 127)) * HD + j];
        else         v = lin_W[(l * HD + (k - 384)) * HD + j];
        Wcat[idx] = v;
    }
}

// ---------------- encoder ----------------
// block = 256 threads, 32 same-type nodes (type-bucketed, 32-padded node list)

#define FMA16(A, v0, v1, v2, v3, w)                                       \
    A[0] += v0.x * w; A[1] += v0.y * w; A[2] += v0.z * w; A[3] += v0.w * w; \
    A[4] += v1.x * w; A[5] += v1.y * w; A[6] += v1.z * w; A[7] += v1.w * w; \
    A[8] += v2.x * w; A[9] += v2.y * w; A[10] += v2.z * w; A[11] += v2.w * w; \
    A[12] += v3.x * w; A[13] += v3.y * w; A[14] += v3.z * w; A[15] += v3.w * w;

__global__ __launch_bounds__(256) void k_enc(
        const unsigned* nodelist, const int* z, const float* sd, const float* df,
        const float* cond, const float* mult, const float* z_embed,
        const float* W1, const float* b1, const float* W2, const float* b2,
        float* xout) {
    __shared__ float raw[32][20];
    __shared__ float h1[128][36];
    __shared__ unsigned ent[32];
    int tid = threadIdx.x;
    int base = blockIdx.x * 32;
    if (tid < 32) ent[tid] = nodelist[base + tid];
    __syncthreads();
    if (ent[0] == 0xFFFFFFFFu) return;  // all-pad block (uniform)
    int type = (int)(ent[0] >> 17);

    for (int idx = tid; idx < 32 * 20; idx += 256) {
        int nl = idx / 20, f = idx - nl * 20;
        unsigned e = ent[nl];
        float v = 0.f;
        if (e != 0xFFFFFFFFu) {
            int node = (int)(e & 0x1FFFF);
            if (f < 16)      v = z_embed[z[node] * 16 + f];
            else if (f == 16) v = sd[node];
            else if (f == 17) v = df[node];
            else if (f == 18) v = cond[node];
            else              v = mult[node];
        }
        raw[nl][f] = v;
    }
    __syncthreads();

    int j = tid & 127, n0 = (tid >> 7) * 16;
    const float* W1t = W1 + type * IND * HD;
    const float* W2t = W2 + type * HD * HD;

    float acc[16];
#pragma unroll
    for (int i = 0; i < 16; i++) acc[i] = 0.f;
    for (int k = 0; k < IND; k++) {
        float w = W1t[k * HD + j];
#pragma unroll
        for (int i = 0; i < 16; i++) acc[i] += raw[n0 + i][k] * w;
    }
    float bb = b1[type * HD + j];
#pragma unroll
    for (int i = 0; i < 16; i++) h1[j][n0 + i] = fmaxf(acc[i] + bb, 0.f);
    __syncthreads();

#pragma unroll
    for (int i = 0; i < 16; i++) acc[i] = 0.f;
    for (int k = 0; k < HD; k++) {
        float w = W2t[k * HD + j];
        const float4* hp = (const float4*)&h1[k][n0];
        float4 v0 = hp[0], v1 = hp[1], v2 = hp[2], v3 = hp[3];
        FMA16(acc, v0, v1, v2, v3, w)
    }
    float b2v = b2[type * HD + j];
#pragma unroll
    for (int i = 0; i < 16; i++) {
        unsigned e = ent[n0 + i];
        if (e != 0xFFFFFFFFu) {
            int node = (int)(e & 0x1FFFF);
            xout[node * HD + j] = acc[i] + b2v;
        }
    }
}

// ---------------- phase A: wave-per-node relation-bucketed aggregation ----------------
// One 64-lane wave per node (float2 per lane), 4 independent waves per block,
// grid-stride, no LDS, no barriers. Edge words are wave-uniform scalar loads;
// x-row gathers unrolled 4-deep for MLP (memory-level parallelism).

#define AGG_BLOCKS 2048

#define ACCSEL(r, v)                                   \
    a0.x += ((r) == 0) ? (v).x : 0.f;                  \
    a0.y += ((r) == 0) ? (v).y : 0.f;                  \
    a1.x += ((r) == 1) ? (v).x : 0.f;                  \
    a1.y += ((r) == 1) ? (v).y : 0.f;                  \
    a2.x += ((r) == 2) ? (v).x : 0.f;                  \
    a2.y += ((r) == 2) ? (v).y : 0.f;

__global__ __launch_bounds__(256) void k_agg(
        const float* __restrict__ x, const unsigned* __restrict__ packed,
        const int* __restrict__ off, const int* __restrict__ cnt,
        const float* __restrict__ inv_deg, float* __restrict__ Y, int node_base) {
    int lane = threadIdx.x & 63;
    int wave = (blockIdx.x * blockDim.x + threadIdx.x) >> 6;
    int nwaves = (AGG_BLOCKS * 256) >> 6;
    const float2* xp = (const float2*)x;

    for (int idx = wave; idx < CHUNK; idx += nwaves) {
        int node = node_base + idx;
        int o = __builtin_amdgcn_readfirstlane(off[node]);
        int c = __builtin_amdgcn_readfirstlane(cnt[node]);

        float2 a0 = {0.f, 0.f}, a1 = {0.f, 0.f}, a2 = {0.f, 0.f};
        float2 xv = xp[(size_t)node * 64 + lane];

        int i = 0;
        for (; i + 4 <= c; i += 4) {
            unsigned e0 = packed[o + i];
            unsigned e1 = packed[o + i + 1];
            unsigned e2 = packed[o + i + 2];
            unsigned e3 = packed[o + i + 3];
            float2 v0 = xp[(size_t)(e0 & 0x1FFFF) * 64 + lane];
            float2 v1 = xp[(size_t)(e1 & 0x1FFFF) * 64 + lane];
            float2 v2 = xp[(size_t)(e2 & 0x1FFFF) * 64 + lane];
            float2 v3 = xp[(size_t)(e3 & 0x1FFFF) * 64 + lane];
            int r0 = (int)(e0 >> 17), r1 = (int)(e1 >> 17);
            int r2 = (int)(e2 >> 17), r3 = (int)(e3 >> 17);
            ACCSEL(r0, v0) ACCSEL(r1, v1) ACCSEL(r2, v2) ACCSEL(r3, v3)
        }
        for (; i < c; i++) {
            unsigned e = packed[o + i];
            float2 v = xp[(size_t)(e & 0x1FFFF) * 64 + lane];
            int r = (int)(e >> 17);
            ACCSEL(r, v)
        }

        float id = inv_deg[node];
        float2* yr = (float2*)(Y + (size_t)idx * 512);
        float2 w0 = {a0.x * id, a0.y * id};
        float2 w1 = {a1.x * id, a1.y * id};
        float2 w2 = {a2.x * id, a2.y * id};
        yr[lane] = w0; yr[64 + lane] = w1; yr[128 + lane] = w2; yr[192 + lane] = xv;
    }
}

// ---------------- phase B: [32,512]x[512,128] GEMM + bias + LayerNorm ----------------

__global__ __launch_bounds__(256) void k_gemm_ln(
        const float* Y, const float* Wc, const float* lb,
        const float* g, const float* bta, float* xout,
        int node_base, int nvalid) {
    __shared__ float ylds[128][36];
    __shared__ float hlds[32][132];
    __shared__ float stat[32][2];
    int tid = threadIdx.x;
    int nb = blockIdx.x * 32;
    int j = tid & 127, n0 = (tid >> 7) * 16;

    float acc[16];
#pragma unroll
    for (int i = 0; i < 16; i++) acc[i] = 0.f;

    int ln = tid >> 3;           // 0..31  (load-phase node)
    int kb = (tid & 7) * 16;     // 0..112 (load-phase k base)

    for (int kc = 0; kc < 4; kc++) {
        __syncthreads();
        const float* yp = Y + (size_t)(nb + ln) * 512 + kc * 128 + kb;
#pragma unroll
        for (int i = 0; i < 16; i += 4) {
            float4 v = *(const float4*)(yp + i);
            ylds[kb + i][ln] = v.x; ylds[kb + i + 1][ln] = v.y;
            ylds[kb + i + 2][ln] = v.z; ylds[kb + i + 3][ln] = v.w;
        }
        __syncthreads();
        const float* wp = Wc + (kc * 128) * HD + j;
        for (int k = 0; k < 128; k++) {
            float w = wp[k * HD];
            const float4* a = (const float4*)&ylds[k][n0];
            float4 v0 = a[0], v1 = a[1], v2 = a[2], v3 = a[3];
            FMA16(acc, v0, v1, v2, v3, w)
        }
    }

    float bj = lb[j];
#pragma unroll
    for (int i = 0; i < 16; i++) hlds[n0 + i][j] = acc[i] + bj;
    __syncthreads();

    {
        int node = tid >> 3, l8 = tid & 7;
        float s = 0.f, ss = 0.f;
#pragma unroll
        for (int i = 0; i < 16; i++) {
            float v = hlds[node][l8 + 8 * i];
            s += v; ss += v * v;
        }
        for (int d = 4; d >= 1; d >>= 1) {
            s += __shfl_down(s, d, 8);
            ss += __shfl_down(ss, d, 8);
        }
        if (l8 == 0) {
            float mu = s * (1.f / 128.f);
            float var = ss * (1.f / 128.f) - mu * mu;
            stat[node][0] = mu;
            stat[node][1] = rsqrtf(var + LNEPS);
        }
    }
    __syncthreads();

    float gj = g[j], btj = bta[j];
#pragma unroll
    for (int i = 0; i < 16; i++) {
        int nl = nb + n0 + i;
        if (nl < nvalid) {
            float mu = stat[n0 + i][0], rs = stat[n0 + i][1];
            float hv = acc[i] + bj;
            xout[(size_t)(node_base + nl) * HD + j] = (hv - mu) * rs * gj + btj;
        }
    }
}

// ---------------- pooling + regressor ----------------

__global__ __launch_bounds__(256) void k_pool(const float* x, const float* regW, float* out) {
    int tid = threadIdx.x;
    int j = tid & 127;
    float s = 0.f;
    int node = blockIdx.x * 2 + (tid >> 7);
    for (; node < NN; node += gridDim.x * 2) s += x[(size_t)node * HD + j];
    s *= regW[j];
    __shared__ float red[4];
    for (int d = 32; d >= 1; d >>= 1) s += __shfl_down(s, d, 64);
    if ((tid & 63) == 0) red[tid >> 6] = s;
    __syncthreads();
    if (tid == 0) {
        float t = red[0] + red[1] + red[2] + red[3];
        atomicAdd(out, t * (1.0f / (float)NN));
    }
}

// ---------------- launcher ----------------

extern "C" void kernel_launch(void* const* d_in, const int* in_sizes, int n_in,
                              void* d_out, int out_size, void* d_ws, size_t ws_size,
                              hipStream_t stream) {
    const int*   z       = (const int*)d_in[0];
    const float* sd      = (const float*)d_in[1];
    const float* df      = (const float*)d_in[2];
    const float* cond    = (const float*)d_in[3];
    const float* mult    = (const float*)d_in[4];
    const int*   nt      = (const int*)d_in[5];
    const int*   ei      = (const int*)d_in[6];
    const int*   et      = (const int*)d_in[7];
    const float* z_embed = (const float*)d_in[8];
    const float* enc_W1  = (const float*)d_in[9];
    const float* enc_b1  = (const float*)d_in[10];
    const float* enc_W2  = (const float*)d_in[11];
    const float* enc_b2  = (const float*)d_in[12];
    const float* lin_W   = (const float*)d_in[13];
    const float* lin_b   = (const float*)d_in[14];
    const float* rel_W   = (const float*)d_in[15];
    const float* ln_g    = (const float*)d_in[16];
    const float* ln_b    = (const float*)d_in[17];
    const float* reg_W   = (const float*)d_in[18];
    const float* reg_b   = (const float*)d_in[19];
    float* out = (float*)d_out;

    char* p = (char*)d_ws;
    int* cnt        = (int*)p;      p += (size_t)NN * 4;
    int* off        = (int*)p;      p += (size_t)NN * 4;
    int* fill_n     = (int*)p;      p += (size_t)NN * 4;
    int* misc       = (int*)p;      p += 16 * 4;        // cnt4[4] off4[4] fill4[4] ctr[2] pad
    unsigned* packed   = (unsigned*)p; p += (size_t)NE * 4;
    unsigned* nodelist = (unsigned*)p; p += (size_t)NLIST * 4;
    float* inv_deg  = (float*)p;    p += (size_t)NN * 4;
    float* Wcat     = (float*)p;    p += (size_t)2 * 512 * 128 * 4;
    float* x0       = (float*)p;    p += (size_t)NN * HD * 4;
    float* x1       = (float*)p;    p += (size_t)NN * HD * 4;
    float* Y        = (float*)p;    p += (size_t)YPAD * 512 * 4;

    k_init<<<400, 256, 0, stream>>>(cnt, fill_n, misc, nodelist, out, reg_b);
    k_count<<<2048, 256, 0, stream>>>(ei, nt, cnt, misc);
    k_alloc<<<400, 256, 0, stream>>>(cnt, off, inv_deg, misc);
    k_fill<<<2048, 256, 0, stream>>>(ei, et, nt, off, fill_n, misc, packed, nodelist);
    k_wcat<<<512, 256, 0, stream>>>(rel_W, lin_W, Wcat);
    k_enc<<<3129, 256, 0, stream>>>(nodelist, z, sd, df, cond, mult, z_embed,
                                    enc_W1, enc_b1, enc_W2, enc_b2, x0);

    float* xin = x0; float* xout = x1;
    for (int l = 0; l < 2; l++) {
        for (int c = 0; c < 4; c++) {
            int base = c * CHUNK;
            k_agg<<<AGG_BLOCKS, 256, 0, stream>>>(xin, packed, off, cnt, inv_deg, Y, base);
            k_gemm_ln<<<782, 256, 0, stream>>>(Y, Wcat + (size_t)l * 512 * 128,
                                               lin_b + l * HD, ln_g + l * HD, ln_b + l * HD,
                                               xout, base, CHUNK);
        }
        float* t = xin; xin = xout; xout = t;
    }
    k_pool<<<256, 256, 0, stream>>>(xin, reg_W, out);
}

// Round 3
// 1526.733 us; speedup vs baseline: 1.7439x; 1.7153x over previous
//
#include <hip/hip_runtime.h>

#define NN 100000
#define NE 1600000
#define HD 128
#define IND 20
#define LNEPS 1e-5f
#define NLIST 100128   // 3129 blocks * 32
#define CHUNK 25000
#define YPAD 25024     // 782*32
#define SCAN_B 391     // ceil(NN/256)
#define FILL_PASSES 8
#define REGION 12500

// ---------------- setup kernels ----------------

__global__ void k_init(int* cnt, int* misc, unsigned* nodelist,
                       float* out, const float* reg_b) {
    int i = blockIdx.x * blockDim.x + threadIdx.x;
    int st = gridDim.x * blockDim.x;
    for (int k = i; k < NN; k += st) cnt[k] = 0;
    for (int k = i; k < NLIST; k += st) nodelist[k] = 0xFFFFFFFFu;
    if (i < 16) misc[i] = 0;
    if (i == 0) out[0] = reg_b[0];
}

// count edges per dst (rank via atomic return, stored coalesced) + type histogram
__global__ void k_count(const int* __restrict__ ei, const int* __restrict__ nt,
                        int* cnt, int* __restrict__ rank, int* misc) {
    int i = blockIdx.x * blockDim.x + threadIdx.x;
    int st = gridDim.x * blockDim.x;
    for (int e = i; e < NE; e += st) {
        int d = ei[NE + e];
        rank[e] = atomicAdd(&cnt[d], 1);
    }
    int lane = threadIdx.x & 63;
    for (int n = i; n < NN; n += st) {
        int t = nt[n];
#pragma unroll
        for (int tt = 0; tt < 4; tt++) {
            unsigned long long m = __ballot(t == tt);
            if (t == tt && lane == (__ffsll((unsigned long long)m) - 1))
                atomicAdd(&misc[tt], (int)__popcll(m));
        }
    }
}

// exact exclusive prefix sum over cnt -> off (monotone in d)
__global__ __launch_bounds__(256) void k_scan1(const int* cnt, int* off, int* bsum) {
    __shared__ int s[256];
    int tid = threadIdx.x;
    int i = blockIdx.x * 256 + tid;
    int v = (i < NN) ? cnt[i] : 0;
    s[tid] = v;
    __syncthreads();
    for (int o = 1; o < 256; o <<= 1) {
        int t = (tid >= o) ? s[tid - o] : 0;
        __syncthreads();
        s[tid] += t;
        __syncthreads();
    }
    if (i < NN) off[i] = s[tid] - v;
    if (tid == 255) bsum[blockIdx.x] = s[255];
}

__global__ __launch_bounds__(512) void k_scan2(int* bsum, int* misc) {
    __shared__ int s[512];
    int tid = threadIdx.x;
    int v = (tid < SCAN_B) ? bsum[tid] : 0;
    s[tid] = v;
    __syncthreads();
    for (int o = 1; o < 512; o <<= 1) {
        int t = (tid >= o) ? s[tid - o] : 0;
        __syncthreads();
        s[tid] += t;
        __syncthreads();
    }
    if (tid < SCAN_B) bsum[tid] = s[tid] - v;
    if (tid == 0) {
        int base = 0;
        for (int t = 0; t < 4; t++) { misc[4 + t] = base; base += (misc[t] + 31) & ~31; }
    }
}

__global__ __launch_bounds__(256) void k_scan3(const int* cnt, int* off,
                                               const int* bsum, float* inv_deg) {
    int i = blockIdx.x * 256 + threadIdx.x;
    if (i < NN) {
        off[i] += bsum[blockIdx.x];
        int c = cnt[i];
        inv_deg[i] = 1.0f / (float)(c > 0 ? c : 1);
    }
}

// atomic-free windowed scatter: pass p only writes dst-region p -> L2-hot 800KB window
__global__ __launch_bounds__(256) void k_fill_e(const int* __restrict__ ei,
                                                const int* __restrict__ et,
                                                const int* __restrict__ off,
                                                const int* __restrict__ rank,
                                                unsigned* __restrict__ packed) {
    int i = blockIdx.x * blockDim.x + threadIdx.x;
    int st = gridDim.x * blockDim.x;
    for (int p = 0; p < FILL_PASSES; p++) {
        int lo = p * REGION;
        for (int e = i; e < NE; e += st) {
            int d = ei[NE + e];
            if ((unsigned)(d - lo) < (unsigned)REGION) {
                packed[off[d] + rank[e]] = (unsigned)ei[e] | ((unsigned)et[e] << 17);
            }
        }
    }
}

// type-bucketed node list via wave-aggregated atomics
__global__ __launch_bounds__(256) void k_fill_n(const int* __restrict__ nt,
                                                int* misc, unsigned* nodelist) {
    int i = blockIdx.x * blockDim.x + threadIdx.x;
    int st = gridDim.x * blockDim.x;
    int lane = threadIdx.x & 63;
    int bases[4] = {misc[4], misc[5], misc[6], misc[7]};
    for (int n = i; n < NN; n += st) {
        int t = nt[n];
#pragma unroll
        for (int tt = 0; tt < 4; tt++) {
            unsigned long long m = __ballot(t == tt);
            if (t == tt) {
                int leader = __ffsll((unsigned long long)m) - 1;
                int base = 0;
                if (lane == leader) base = atomicAdd(&misc[8 + tt], (int)__popcll(m));
                base = __shfl(base, leader);
                int prefix = (int)__popcll(m & (((unsigned long long)1 << lane) - 1));
                nodelist[bases[tt] + base + prefix] = (unsigned)n | ((unsigned)tt << 17);
            }
        }
    }
}

__global__ void k_wcat(const float* rel_W, const float* lin_W, float* Wcat) {
    int i = blockIdx.x * blockDim.x + threadIdx.x;
    int st = gridDim.x * blockDim.x;
    for (int idx = i; idx < 2 * 512 * 128; idx += st) {
        int l = idx >> 16;
        int rem = idx & 65535;
        int k = rem >> 7, j = rem & 127;
        float v;
        if (k < 384) v = rel_W[((l * 3 + (k >> 7)) * HD + (k & 127)) * HD + j];
        else         v = lin_W[(l * HD + (k - 384)) * HD + j];
        Wcat[idx] = v;
    }
}

// ---------------- encoder ----------------

#define FMA16(A, v0, v1, v2, v3, w)                                       \
    A[0] += v0.x * w; A[1] += v0.y * w; A[2] += v0.z * w; A[3] += v0.w * w; \
    A[4] += v1.x * w; A[5] += v1.y * w; A[6] += v1.z * w; A[7] += v1.w * w; \
    A[8] += v2.x * w; A[9] += v2.y * w; A[10] += v2.z * w; A[11] += v2.w * w; \
    A[12] += v3.x * w; A[13] += v3.y * w; A[14] += v3.z * w; A[15] += v3.w * w;

__global__ __launch_bounds__(256) void k_enc(
        const unsigned* nodelist, const int* z, const float* sd, const float* df,
        const float* cond, const float* mult, const float* z_embed,
        const float* W1, const float* b1, const float* W2, const float* b2,
        float* xout) {
    __shared__ float raw[32][20];
    __shared__ float h1[128][36];
    __shared__ unsigned ent[32];
    int tid = threadIdx.x;
    int base = blockIdx.x * 32;
    if (tid < 32) ent[tid] = nodelist[base + tid];
    __syncthreads();
    if (ent[0] == 0xFFFFFFFFu) return;
    int type = (int)(ent[0] >> 17);

    for (int idx = tid; idx < 32 * 20; idx += 256) {
        int nl = idx / 20, f = idx - nl * 20;
        unsigned e = ent[nl];
        float v = 0.f;
        if (e != 0xFFFFFFFFu) {
            int node = (int)(e & 0x1FFFF);
            if (f < 16)      v = z_embed[z[node] * 16 + f];
            else if (f == 16) v = sd[node];
            else if (f == 17) v = df[node];
            else if (f == 18) v = cond[node];
            else              v = mult[node];
        }
        raw[nl][f] = v;
    }
    __syncthreads();

    int j = tid & 127, n0 = (tid >> 7) * 16;
    const float* W1t = W1 + type * IND * HD;
    const float* W2t = W2 + type * HD * HD;

    float acc[16];
#pragma unroll
    for (int i = 0; i < 16; i++) acc[i] = 0.f;
    for (int k = 0; k < IND; k++) {
        float w = W1t[k * HD + j];
#pragma unroll
        for (int i = 0; i < 16; i++) acc[i] += raw[n0 + i][k] * w;
    }
    float bb = b1[type * HD + j];
#pragma unroll
    for (int i = 0; i < 16; i++) h1[j][n0 + i] = fmaxf(acc[i] + bb, 0.f);
    __syncthreads();

#pragma unroll
    for (int i = 0; i < 16; i++) acc[i] = 0.f;
    for (int k = 0; k < HD; k++) {
        float w = W2t[k * HD + j];
        const float4* hp = (const float4*)&h1[k][n0];
        float4 v0 = hp[0], v1 = hp[1], v2 = hp[2], v3 = hp[3];
        FMA16(acc, v0, v1, v2, v3, w)
    }
    float b2v = b2[type * HD + j];
#pragma unroll
    for (int i = 0; i < 16; i++) {
        unsigned e = ent[n0 + i];
        if (e != 0xFFFFFFFFu) {
            int node = (int)(e & 0x1FFFF);
            xout[node * HD + j] = acc[i] + b2v;
        }
    }
}

// ---------------- phase A: wave-per-node aggregation ----------------

#define AGG_BLOCKS 2048

#define ACCSEL(r, v)                                   \
    a0.x += ((r) == 0) ? (v).x : 0.f;                  \
    a0.y += ((r) == 0) ? (v).y : 0.f;                  \
    a1.x += ((r) == 1) ? (v).x : 0.f;                  \
    a1.y += ((r) == 1) ? (v).y : 0.f;                  \
    a2.x += ((r) == 2) ? (v).x : 0.f;                  \
    a2.y += ((r) == 2) ? (v).y : 0.f;

__global__ __launch_bounds__(256) void k_agg(
        const float* __restrict__ x, const unsigned* __restrict__ packed,
        const int* __restrict__ off, const int* __restrict__ cnt,
        const float* __restrict__ inv_deg, float* __restrict__ Y, int node_base) {
    int lane = threadIdx.x & 63;
    int wave = (blockIdx.x * blockDim.x + threadIdx.x) >> 6;
    int nwaves = (AGG_BLOCKS * 256) >> 6;
    const float2* xp = (const float2*)x;

    for (int idx = wave; idx < CHUNK; idx += nwaves) {
        int node = node_base + idx;
        int o = __builtin_amdgcn_readfirstlane(off[node]);
        int c = __builtin_amdgcn_readfirstlane(cnt[node]);

        float2 a0 = {0.f, 0.f}, a1 = {0.f, 0.f}, a2 = {0.f, 0.f};
        float2 xv = xp[(size_t)node * 64 + lane];

        int i = 0;
        for (; i + 4 <= c; i += 4) {
            unsigned e0 = packed[o + i];
            unsigned e1 = packed[o + i + 1];
            unsigned e2 = packed[o + i + 2];
            unsigned e3 = packed[o + i + 3];
            float2 v0 = xp[(size_t)(e0 & 0x1FFFF) * 64 + lane];
            float2 v1 = xp[(size_t)(e1 & 0x1FFFF) * 64 + lane];
            float2 v2 = xp[(size_t)(e2 & 0x1FFFF) * 64 + lane];
            float2 v3 = xp[(size_t)(e3 & 0x1FFFF) * 64 + lane];
            int r0 = (int)(e0 >> 17), r1 = (int)(e1 >> 17);
            int r2 = (int)(e2 >> 17), r3 = (int)(e3 >> 17);
            ACCSEL(r0, v0) ACCSEL(r1, v1) ACCSEL(r2, v2) ACCSEL(r3, v3)
        }
        for (; i < c; i++) {
            unsigned e = packed[o + i];
            float2 v = xp[(size_t)(e & 0x1FFFF) * 64 + lane];
            int r = (int)(e >> 17);
            ACCSEL(r, v)
        }

        float id = inv_deg[node];
        float2* yr = (float2*)(Y + (size_t)idx * 512);
        float2 w0 = {a0.x * id, a0.y * id};
        float2 w1 = {a1.x * id, a1.y * id};
        float2 w2 = {a2.x * id, a2.y * id};
        yr[lane] = w0; yr[64 + lane] = w1; yr[128 + lane] = w2; yr[192 + lane] = xv;
    }
}

// ---------------- phase B: [32,512]x[512,128] GEMM + bias + LayerNorm ----------------

__global__ __launch_bounds__(256) void k_gemm_ln(
        const float* Y, const float* Wc, const float* lb,
        const float* g, const float* bta, float* xout,
        int node_base, int nvalid) {
    __shared__ float ylds[128][36];
    __shared__ float hlds[32][132];
    __shared__ float stat[32][2];
    int tid = threadIdx.x;
    int nb = blockIdx.x * 32;
    int j = tid & 127, n0 = (tid >> 7) * 16;

    float acc[16];
#pragma unroll
    for (int i = 0; i < 16; i++) acc[i] = 0.f;

    int ln = tid >> 3;
    int kb = (tid & 7) * 16;

    for (int kc = 0; kc < 4; kc++) {
        __syncthreads();
        const float* yp = Y + (size_t)(nb + ln) * 512 + kc * 128 + kb;
#pragma unroll
        for (int i = 0; i < 16; i += 4) {
            float4 v = *(const float4*)(yp + i);
            ylds[kb + i][ln] = v.x; ylds[kb + i + 1][ln] = v.y;
            ylds[kb + i + 2][ln] = v.z; ylds[kb + i + 3][ln] = v.w;
        }
        __syncthreads();
        const float* wp = Wc + (kc * 128) * HD + j;
        for (int k = 0; k < 128; k++) {
            float w = wp[k * HD];
            const float4* a = (const float4*)&ylds[k][n0];
            float4 v0 = a[0], v1 = a[1], v2 = a[2], v3 = a[3];
            FMA16(acc, v0, v1, v2, v3, w)
        }
    }

    float bj = lb[j];
#pragma unroll
    for (int i = 0; i < 16; i++) hlds[n0 + i][j] = acc[i] + bj;
    __syncthreads();

    {
        int node = tid >> 3, l8 = tid & 7;
        float s = 0.f, ss = 0.f;
#pragma unroll
        for (int i = 0; i < 16; i++) {
            float v = hlds[node][l8 + 8 * i];
            s += v; ss += v * v;
        }
        for (int d = 4; d >= 1; d >>= 1) {
            s += __shfl_down(s, d, 8);
            ss += __shfl_down(ss, d, 8);
        }
        if (l8 == 0) {
            float mu = s * (1.f / 128.f);
            float var = ss * (1.f / 128.f) - mu * mu;
            stat[node][0] = mu;
            stat[node][1] = rsqrtf(var + LNEPS);
        }
    }
    __syncthreads();

    float gj = g[j], btj = bta[j];
#pragma unroll
    for (int i = 0; i < 16; i++) {
        int nl = nb + n0 + i;
        if (nl < nvalid) {
            float mu = stat[n0 + i][0], rs = stat[n0 + i][1];
            float hv = acc[i] + bj;
            xout[(size_t)(node_base + nl) * HD + j] = (hv - mu) * rs * gj + btj;
        }
    }
}

// ---------------- pooling + regressor ----------------

__global__ __launch_bounds__(256) void k_pool(const float* x, const float* regW, float* out) {
    int tid = threadIdx.x;
    int j = tid & 127;
    float s = 0.f;
    int node = blockIdx.x * 2 + (tid >> 7);
    for (; node < NN; node += gridDim.x * 2) s += x[(size_t)node * HD + j];
    s *= regW[j];
    __shared__ float red[4];
    for (int d = 32; d >= 1; d >>= 1) s += __shfl_down(s, d, 64);
    if ((tid & 63) == 0) red[tid >> 6] = s;
    __syncthreads();
    if (tid == 0) {
        float t = red[0] + red[1] + red[2] + red[3];
        atomicAdd(out, t * (1.0f / (float)NN));
    }
}

// ---------------- launcher ----------------

extern "C" void kernel_launch(void* const* d_in, const int* in_sizes, int n_in,
                              void* d_out, int out_size, void* d_ws, size_t ws_size,
                              hipStream_t stream) {
    const int*   z       = (const int*)d_in[0];
    const float* sd      = (const float*)d_in[1];
    const float* df      = (const float*)d_in[2];
    const float* cond    = (const float*)d_in[3];
    const float* mult    = (const float*)d_in[4];
    const int*   nt      = (const int*)d_in[5];
    const int*   ei      = (const int*)d_in[6];
    const int*   et      = (const int*)d_in[7];
    const float* z_embed = (const float*)d_in[8];
    const float* enc_W1  = (const float*)d_in[9];
    const float* enc_b1  = (const float*)d_in[10];
    const float* enc_W2  = (const float*)d_in[11];
    const float* enc_b2  = (const float*)d_in[12];
    const float* lin_W   = (const float*)d_in[13];
    const float* lin_b   = (const float*)d_in[14];
    const float* rel_W   = (const float*)d_in[15];
    const float* ln_g    = (const float*)d_in[16];
    const float* ln_b    = (const float*)d_in[17];
    const float* reg_W   = (const float*)d_in[18];
    const float* reg_b   = (const float*)d_in[19];
    float* out = (float*)d_out;

    char* p = (char*)d_ws;
    int* cnt        = (int*)p;      p += (size_t)NN * 4;
    int* off        = (int*)p;      p += (size_t)NN * 4;
    int* rank       = (int*)p;      p += (size_t)NE * 4;
    int* misc       = (int*)p;      p += 16 * 4;
    int* bsum       = (int*)p;      p += 512 * 4;
    unsigned* packed   = (unsigned*)p; p += (size_t)NE * 4;
    unsigned* nodelist = (unsigned*)p; p += (size_t)NLIST * 4;
    float* inv_deg  = (float*)p;    p += (size_t)NN * 4;
    float* Wcat     = (float*)p;    p += (size_t)2 * 512 * 128 * 4;
    float* x0       = (float*)p;    p += (size_t)NN * HD * 4;
    float* x1       = (float*)p;    p += (size_t)NN * HD * 4;
    float* Y        = (float*)p;    p += (size_t)YPAD * 512 * 4;

    k_init<<<400, 256, 0, stream>>>(cnt, misc, nodelist, out, reg_b);
    k_count<<<2048, 256, 0, stream>>>(ei, nt, cnt, rank, misc);
    k_scan1<<<SCAN_B, 256, 0, stream>>>(cnt, off, bsum);
    k_scan2<<<1, 512, 0, stream>>>(bsum, misc);
    k_scan3<<<SCAN_B, 256, 0, stream>>>(cnt, off, bsum, inv_deg);
    k_fill_e<<<2048, 256, 0, stream>>>(ei, et, off, rank, packed);
    k_fill_n<<<400, 256, 0, stream>>>(nt, misc, nodelist);
    k_wcat<<<512, 256, 0, stream>>>(rel_W, lin_W, Wcat);
    k_enc<<<3129, 256, 0, stream>>>(nodelist, z, sd, df, cond, mult, z_embed,
                                    enc_W1, enc_b1, enc_W2, enc_b2, x0);

    float* xin = x0; float* xout = x1;
    for (int l = 0; l < 2; l++) {
        for (int c = 0; c < 4; c++) {
            int base = c * CHUNK;
            k_agg<<<AGG_BLOCKS, 256, 0, stream>>>(xin, packed, off, cnt, inv_deg, Y, base);
            k_gemm_ln<<<782, 256, 0, stream>>>(Y, Wcat + (size_t)l * 512 * 128,
                                               lin_b + l * HD, ln_g + l * HD, ln_b + l * HD,
                                               xout, base, CHUNK);
        }
        float* t = xin; xin = xout; xout = t;
    }
    k_pool<<<256, 256, 0, stream>>>(xin, reg_W, out);
}

// Round 4
// 1136.745 us; speedup vs baseline: 2.3422x; 1.3431x over previous
//
#include <hip/hip_runtime.h>

#define NN 100000
#define NE 1600000
#define HD 128
#define IND 20
#define LNEPS 1e-5f
#define NLIST 100128   // 3129 blocks * 32
#define SCAN_B 391     // ceil(NN/256)
#define FILL_PASSES 8
#define REGION 12500

typedef unsigned int uint32;
typedef unsigned short ushort16;

__device__ __forceinline__ float2 bf2f(uint32 u) {
    float2 r;
    r.x = __uint_as_float(u << 16);
    r.y = __uint_as_float(u & 0xffff0000u);
    return r;
}
__device__ __forceinline__ ushort16 f2bf(float f) {
    uint32 u = __float_as_uint(f);
    u += 0x7fffu + ((u >> 16) & 1u);   // round-to-nearest-even
    return (ushort16)(u >> 16);
}

// ---------------- setup kernels ----------------

__global__ void k_init(int* cnt, int* misc, unsigned* nodelist,
                       float* out, const float* reg_b) {
    int i = blockIdx.x * blockDim.x + threadIdx.x;
    int st = gridDim.x * blockDim.x;
    for (int k = i; k < NN; k += st) cnt[k] = 0;
    for (int k = i; k < NLIST; k += st) nodelist[k] = 0xFFFFFFFFu;
    if (i < 16) misc[i] = 0;
    if (i == 0) out[0] = reg_b[0];
}

// count edges per dst (rank via atomic return, stored coalesced) + type histogram
__global__ void k_count(const int* __restrict__ ei, const int* __restrict__ nt,
                        int* cnt, int* __restrict__ rank, int* misc) {
    int i = blockIdx.x * blockDim.x + threadIdx.x;
    int st = gridDim.x * blockDim.x;
    for (int e = i; e < NE; e += st) {
        int d = ei[NE + e];
        rank[e] = atomicAdd(&cnt[d], 1);
    }
    int lane = threadIdx.x & 63;
    for (int n = i; n < NN; n += st) {
        int t = nt[n];
#pragma unroll
        for (int tt = 0; tt < 4; tt++) {
            unsigned long long m = __ballot(t == tt);
            if (t == tt && lane == (__ffsll((unsigned long long)m) - 1))
                atomicAdd(&misc[tt], (int)__popcll(m));
        }
    }
}

// exact exclusive prefix sum over cnt -> off (monotone in d)
__global__ __launch_bounds__(256) void k_scan1(const int* cnt, int* off, int* bsum) {
    __shared__ int s[256];
    int tid = threadIdx.x;
    int i = blockIdx.x * 256 + tid;
    int v = (i < NN) ? cnt[i] : 0;
    s[tid] = v;
    __syncthreads();
    for (int o = 1; o < 256; o <<= 1) {
        int t = (tid >= o) ? s[tid - o] : 0;
        __syncthreads();
        s[tid] += t;
        __syncthreads();
    }
    if (i < NN) off[i] = s[tid] - v;
    if (tid == 255) bsum[blockIdx.x] = s[255];
}

__global__ __launch_bounds__(512) void k_scan2(int* bsum, int* misc) {
    __shared__ int s[512];
    int tid = threadIdx.x;
    int v = (tid < SCAN_B) ? bsum[tid] : 0;
    s[tid] = v;
    __syncthreads();
    for (int o = 1; o < 512; o <<= 1) {
        int t = (tid >= o) ? s[tid - o] : 0;
        __syncthreads();
        s[tid] += t;
        __syncthreads();
    }
    if (tid < SCAN_B) bsum[tid] = s[tid] - v;
    if (tid == 0) {
        int base = 0;
        for (int t = 0; t < 4; t++) { misc[4 + t] = base; base += (misc[t] + 31) & ~31; }
    }
}

__global__ __launch_bounds__(256) void k_scan3(const int* cnt, int* off,
                                               const int* bsum, float* inv_deg) {
    int i = blockIdx.x * 256 + threadIdx.x;
    if (i < NN) {
        off[i] += bsum[blockIdx.x];
        int c = cnt[i];
        inv_deg[i] = 1.0f / (float)(c > 0 ? c : 1);
    }
}

// atomic-free windowed scatter: pass p only writes dst-region p -> L2-hot window
__global__ __launch_bounds__(256) void k_fill_e(const int* __restrict__ ei,
                                                const int* __restrict__ et,
                                                const int* __restrict__ off,
                                                const int* __restrict__ rank,
                                                unsigned* __restrict__ packed) {
    int i = blockIdx.x * blockDim.x + threadIdx.x;
    int st = gridDim.x * blockDim.x;
    for (int p = 0; p < FILL_PASSES; p++) {
        int lo = p * REGION;
        for (int e = i; e < NE; e += st) {
            int d = ei[NE + e];
            if ((unsigned)(d - lo) < (unsigned)REGION) {
                packed[off[d] + rank[e]] = (unsigned)ei[e] | ((unsigned)et[e] << 17);
            }
        }
    }
}

// type-bucketed node list via wave-aggregated atomics
__global__ __launch_bounds__(256) void k_fill_n(const int* __restrict__ nt,
                                                int* misc, unsigned* nodelist) {
    int i = blockIdx.x * blockDim.x + threadIdx.x;
    int st = gridDim.x * blockDim.x;
    int lane = threadIdx.x & 63;
    int bases[4] = {misc[4], misc[5], misc[6], misc[7]};
    for (int n = i; n < NN; n += st) {
        int t = nt[n];
#pragma unroll
        for (int tt = 0; tt < 4; tt++) {
            unsigned long long m = __ballot(t == tt);
            if (t == tt) {
                int leader = __ffsll((unsigned long long)m) - 1;
                int base = 0;
                if (lane == leader) base = atomicAdd(&misc[8 + tt], (int)__popcll(m));
                base = __shfl(base, leader);
                int prefix = (int)__popcll(m & (((unsigned long long)1 << lane) - 1));
                nodelist[bases[tt] + base + prefix] = (unsigned)n | ((unsigned)tt << 17);
            }
        }
    }
}

__global__ void k_wcat(const float* rel_W, const float* lin_W, float* Wcat) {
    int i = blockIdx.x * blockDim.x + threadIdx.x;
    int st = gridDim.x * blockDim.x;
    for (int idx = i; idx < 2 * 512 * 128; idx += st) {
        int l = idx >> 16;
        int rem = idx & 65535;
        int k = rem >> 7, j = rem & 127;
        float v;
        if (k < 384) v = rel_W[((l * 3 + (k >> 7)) * HD + (k & 127)) * HD + j];
        else         v = lin_W[(l * HD + (k - 384)) * HD + j];
        Wcat[idx] = v;
    }
}

// ---------------- encoder (bf16 output) ----------------

#define FMA16(A, v0, v1, v2, v3, w)                                       \
    A[0] += v0.x * w; A[1] += v0.y * w; A[2] += v0.z * w; A[3] += v0.w * w; \
    A[4] += v1.x * w; A[5] += v1.y * w; A[6] += v1.z * w; A[7] += v1.w * w; \
    A[8] += v2.x * w; A[9] += v2.y * w; A[10] += v2.z * w; A[11] += v2.w * w; \
    A[12] += v3.x * w; A[13] += v3.y * w; A[14] += v3.z * w; A[15] += v3.w * w;

__global__ __launch_bounds__(256) void k_enc(
        const unsigned* nodelist, const int* z, const float* sd, const float* df,
        const float* cond, const float* mult, const float* z_embed,
        const float* W1, const float* b1, const float* W2, const float* b2,
        ushort16* xout) {
    __shared__ float raw[32][20];
    __shared__ float h1[128][36];
    __shared__ unsigned ent[32];
    int tid = threadIdx.x;
    int base = blockIdx.x * 32;
    if (tid < 32) ent[tid] = nodelist[base + tid];
    __syncthreads();
    if (ent[0] == 0xFFFFFFFFu) return;
    int type = (int)(ent[0] >> 17);

    for (int idx = tid; idx < 32 * 20; idx += 256) {
        int nl = idx / 20, f = idx - nl * 20;
        unsigned e = ent[nl];
        float v = 0.f;
        if (e != 0xFFFFFFFFu) {
            int node = (int)(e & 0x1FFFF);
            if (f < 16)      v = z_embed[z[node] * 16 + f];
            else if (f == 16) v = sd[node];
            else if (f == 17) v = df[node];
            else if (f == 18) v = cond[node];
            else              v = mult[node];
        }
        raw[nl][f] = v;
    }
    __syncthreads();

    int j = tid & 127, n0 = (tid >> 7) * 16;
    const float* W1t = W1 + type * IND * HD;
    const float* W2t = W2 + type * HD * HD;

    float acc[16];
#pragma unroll
    for (int i = 0; i < 16; i++) acc[i] = 0.f;
    for (int k = 0; k < IND; k++) {
        float w = W1t[k * HD + j];
#pragma unroll
        for (int i = 0; i < 16; i++) acc[i] += raw[n0 + i][k] * w;
    }
    float bb = b1[type * HD + j];
#pragma unroll
    for (int i = 0; i < 16; i++) h1[j][n0 + i] = fmaxf(acc[i] + bb, 0.f);
    __syncthreads();

#pragma unroll
    for (int i = 0; i < 16; i++) acc[i] = 0.f;
    for (int k = 0; k < HD; k++) {
        float w = W2t[k * HD + j];
        const float4* hp = (const float4*)&h1[k][n0];
        float4 v0 = hp[0], v1 = hp[1], v2 = hp[2], v3 = hp[3];
        FMA16(acc, v0, v1, v2, v3, w)
    }
    float b2v = b2[type * HD + j];
#pragma unroll
    for (int i = 0; i < 16; i++) {
        unsigned e = ent[n0 + i];
        if (e != 0xFFFFFFFFu) {
            int node = (int)(e & 0x1FFFF);
            xout[node * HD + j] = f2bf(acc[i] + b2v);
        }
    }
}

// ---------------- fused layer: aggregate (registers) -> GEMM -> LayerNorm ----------------
// 256 threads = 4 waves; wave w aggregates nodes [nb+8w, nb+8w+8) with lane
// holding features {2*lane, 2*lane+1}; panels transposed through LDS into the
// 512-K GEMM; LN fused in epilogue. x is bf16 (uint = 2 features per lane).

#define ACCSEL(r, v)                                   \
    a0.x += ((r) == 0) ? (v).x : 0.f;                  \
    a0.y += ((r) == 0) ? (v).y : 0.f;                  \
    a1.x += ((r) == 1) ? (v).x : 0.f;                  \
    a1.y += ((r) == 1) ? (v).y : 0.f;                  \
    a2.x += ((r) == 2) ? (v).x : 0.f;                  \
    a2.y += ((r) == 2) ? (v).y : 0.f;

__global__ __launch_bounds__(256) void k_fused(
        const ushort16* __restrict__ x, const unsigned* __restrict__ packed,
        const int* __restrict__ off, const int* __restrict__ cnt,
        const float* __restrict__ inv_deg, const float* __restrict__ Wc,
        const float* __restrict__ lb, const float* __restrict__ g,
        const float* __restrict__ bta, ushort16* __restrict__ xout) {
    __shared__ float smem[128 * 36];     // ylds [128][36], aliased as hlds [32][132]
    __shared__ float stat[32][2];
    int tid = threadIdx.x;
    int lane = tid & 63;
    int wv = tid >> 6;
    int nb = blockIdx.x * 32;

    const uint32* xw = (const uint32*)x;   // one uint (2 bf16) per lane, row stride 64

    float2 pan[4][8];
#pragma unroll
    for (int i = 0; i < 8; i++) {
        int node = nb + wv * 8 + i;
        int o = __builtin_amdgcn_readfirstlane(off[node]);
        int c = __builtin_amdgcn_readfirstlane(cnt[node]);
        float2 a0 = {0.f, 0.f}, a1 = {0.f, 0.f}, a2 = {0.f, 0.f};
        int e = 0;
        for (; e + 4 <= c; e += 4) {
            unsigned q0 = packed[o + e];
            unsigned q1 = packed[o + e + 1];
            unsigned q2 = packed[o + e + 2];
            unsigned q3 = packed[o + e + 3];
            float2 v0 = bf2f(xw[(size_t)(q0 & 0x1FFFF) * 64 + lane]);
            float2 v1 = bf2f(xw[(size_t)(q1 & 0x1FFFF) * 64 + lane]);
            float2 v2 = bf2f(xw[(size_t)(q2 & 0x1FFFF) * 64 + lane]);
            float2 v3 = bf2f(xw[(size_t)(q3 & 0x1FFFF) * 64 + lane]);
            int r0 = (int)(q0 >> 17), r1 = (int)(q1 >> 17);
            int r2 = (int)(q2 >> 17), r3 = (int)(q3 >> 17);
            ACCSEL(r0, v0) ACCSEL(r1, v1) ACCSEL(r2, v2) ACCSEL(r3, v3)
        }
        for (; e < c; e++) {
            unsigned q = packed[o + e];
            float2 v = bf2f(xw[(size_t)(q & 0x1FFFF) * 64 + lane]);
            int r = (int)(q >> 17);
            ACCSEL(r, v)
        }
        float id = inv_deg[node];
        pan[0][i] = make_float2(a0.x * id, a0.y * id);
        pan[1][i] = make_float2(a1.x * id, a1.y * id);
        pan[2][i] = make_float2(a2.x * id, a2.y * id);
        pan[3][i] = bf2f(xw[(size_t)node * 64 + lane]);
    }

    // ---- panel GEMM ----
    float* ylds = smem;                 // [128][36]
    int j = tid & 127, n0 = (tid >> 7) * 16;
    float acc[16];
#pragma unroll
    for (int i = 0; i < 16; i++) acc[i] = 0.f;

#pragma unroll
    for (int kc = 0; kc < 4; kc++) {
        __syncthreads();
#pragma unroll
        for (int i = 0; i < 8; i++) {
            int node = wv * 8 + i;
            ylds[(2 * lane) * 36 + node]     = pan[kc][i].x;
            ylds[(2 * lane + 1) * 36 + node] = pan[kc][i].y;
        }
        __syncthreads();
        const float* wp = Wc + (kc * 128) * HD + j;
        for (int k = 0; k < 128; k++) {
            float w = wp[k * HD];
            const float4* a = (const float4*)&ylds[k * 36 + n0];
            float4 v0 = a[0], v1 = a[1], v2 = a[2], v3 = a[3];
            FMA16(acc, v0, v1, v2, v3, w)
        }
    }

    // ---- bias + LayerNorm (hlds aliases smem) ----
    __syncthreads();
    float* hlds = smem;                 // [32][132]
    float bj = lb[j];
#pragma unroll
    for (int i = 0; i < 16; i++) hlds[(n0 + i) * 132 + j] = acc[i] + bj;
    __syncthreads();

    {
        int node = tid >> 3, l8 = tid & 7;
        float s = 0.f, ss = 0.f;
#pragma unroll
        for (int i = 0; i < 16; i++) {
            float v = hlds[node * 132 + l8 + 8 * i];
            s += v; ss += v * v;
        }
        for (int d = 4; d >= 1; d >>= 1) {
            s += __shfl_down(s, d, 8);
            ss += __shfl_down(ss, d, 8);
        }
        if (l8 == 0) {
            float mu = s * (1.f / 128.f);
            float var = ss * (1.f / 128.f) - mu * mu;
            stat[node][0] = mu;
            stat[node][1] = rsqrtf(var + LNEPS);
        }
    }
    __syncthreads();

    float gj = g[j], btj = bta[j];
#pragma unroll
    for (int i = 0; i < 16; i++) {
        float mu = stat[n0 + i][0], rs = stat[n0 + i][1];
        float hv = acc[i] + bj;
        xout[(size_t)(nb + n0 + i) * HD + j] = f2bf((hv - mu) * rs * gj + btj);
    }
}

// ---------------- pooling + regressor ----------------

__global__ __launch_bounds__(256) void k_pool(const ushort16* __restrict__ x,
                                              const float* regW, float* out) {
    int tid = threadIdx.x;
    int j = tid & 127;
    float s = 0.f;
    int node = blockIdx.x * 2 + (tid >> 7);
    for (; node < NN; node += gridDim.x * 2) {
        uint32 u = (uint32)x[(size_t)node * HD + j];
        s += __uint_as_float(u << 16);
    }
    s *= regW[j];
    __shared__ float red[4];
    for (int d = 32; d >= 1; d >>= 1) s += __shfl_down(s, d, 64);
    if ((tid & 63) == 0) red[tid >> 6] = s;
    __syncthreads();
    if (tid == 0) {
        float t = red[0] + red[1] + red[2] + red[3];
        atomicAdd(out, t * (1.0f / (float)NN));
    }
}

// ---------------- launcher ----------------

extern "C" void kernel_launch(void* const* d_in, const int* in_sizes, int n_in,
                              void* d_out, int out_size, void* d_ws, size_t ws_size,
                              hipStream_t stream) {
    const int*   z       = (const int*)d_in[0];
    const float* sd      = (const float*)d_in[1];
    const float* df      = (const float*)d_in[2];
    const float* cond    = (const float*)d_in[3];
    const float* mult    = (const float*)d_in[4];
    const int*   nt      = (const int*)d_in[5];
    const int*   ei      = (const int*)d_in[6];
    const int*   et      = (const int*)d_in[7];
    const float* z_embed = (const float*)d_in[8];
    const float* enc_W1  = (const float*)d_in[9];
    const float* enc_b1  = (const float*)d_in[10];
    const float* enc_W2  = (const float*)d_in[11];
    const float* enc_b2  = (const float*)d_in[12];
    const float* lin_W   = (const float*)d_in[13];
    const float* lin_b   = (const float*)d_in[14];
    const float* rel_W   = (const float*)d_in[15];
    const float* ln_g    = (const float*)d_in[16];
    const float* ln_b    = (const float*)d_in[17];
    const float* reg_W   = (const float*)d_in[18];
    const float* reg_b   = (const float*)d_in[19];
    float* out = (float*)d_out;

    char* p = (char*)d_ws;
    int* cnt        = (int*)p;      p += (size_t)NN * 4;
    int* off        = (int*)p;      p += (size_t)NN * 4;
    int* rank       = (int*)p;      p += (size_t)NE * 4;
    int* misc       = (int*)p;      p += 16 * 4;
    int* bsum       = (int*)p;      p += 512 * 4;
    unsigned* packed   = (unsigned*)p; p += (size_t)NE * 4;
    unsigned* nodelist = (unsigned*)p; p += (size_t)NLIST * 4;
    float* inv_deg  = (float*)p;    p += (size_t)NN * 4;
    float* Wcat     = (float*)p;    p += (size_t)2 * 512 * 128 * 4;
    ushort16* x0    = (ushort16*)p; p += (size_t)NN * HD * 2;
    ushort16* x1    = (ushort16*)p; p += (size_t)NN * HD * 2;

    k_init<<<400, 256, 0, stream>>>(cnt, misc, nodelist, out, reg_b);
    k_count<<<2048, 256, 0, stream>>>(ei, nt, cnt, rank, misc);
    k_scan1<<<SCAN_B, 256, 0, stream>>>(cnt, off, bsum);
    k_scan2<<<1, 512, 0, stream>>>(bsum, misc);
    k_scan3<<<SCAN_B, 256, 0, stream>>>(cnt, off, bsum, inv_deg);
    k_fill_e<<<2048, 256, 0, stream>>>(ei, et, off, rank, packed);
    k_fill_n<<<400, 256, 0, stream>>>(nt, misc, nodelist);
    k_wcat<<<512, 256, 0, stream>>>(rel_W, lin_W, Wcat);
    k_enc<<<3129, 256, 0, stream>>>(nodelist, z, sd, df, cond, mult, z_embed,
                                    enc_W1, enc_b1, enc_W2, enc_b2, x0);

    ushort16* xin = x0; ushort16* xo = x1;
    for (int l = 0; l < 2; l++) {
        k_fused<<<NN / 32, 256, 0, stream>>>(xin, packed, off, cnt, inv_deg,
                                             Wcat + (size_t)l * 512 * 128,
                                             lin_b + l * HD, ln_g + l * HD, ln_b + l * HD,
                                             xo);
        ushort16* t = xin; xin = xo; xo = t;
    }
    k_pool<<<256, 256, 0, stream>>>(xin, reg_W, out);
}

// Round 6
// 747.831 us; speedup vs baseline: 3.5603x; 1.5201x over previous
//
#include <hip/hip_runtime.h>

#define NN 100000
#define NE 1600000
#define HD 128
#define IND 20
#define LNEPS 1e-5f
#define NLIST 100128   // 3129 blocks * 32
#define SCAN_B 391     // ceil(NN/256)
#define FILL_PASSES 8
#define REGION 12500
#define ASTRIDE 260    // A-tile row stride in 32-bit words (520 bf16): 16B-aligned

typedef unsigned int uint32;
typedef unsigned short ushort16;
typedef __attribute__((ext_vector_type(8))) short bf16x8;
typedef __attribute__((ext_vector_type(4))) float f32x4;

__device__ __forceinline__ float2 bf2f(uint32 u) {
    float2 r;
    r.x = __uint_as_float(u << 16);
    r.y = __uint_as_float(u & 0xffff0000u);
    return r;
}
__device__ __forceinline__ ushort16 f2bf(float f) {
    uint32 u = __float_as_uint(f);
    u += 0x7fffu + ((u >> 16) & 1u);   // round-to-nearest-even
    return (ushort16)(u >> 16);
}
__device__ __forceinline__ float bf2f1(ushort16 h) {
    return __uint_as_float(((uint32)h) << 16);
}
__device__ __forceinline__ uint32 pack2bf(float2 v) {
    return (uint32)f2bf(v.x) | ((uint32)f2bf(v.y) << 16);
}

// ---------------- setup kernels ----------------

__global__ void k_init(int* cnt, int* misc, unsigned* nodelist,
                       float* out, const float* reg_b) {
    int i = blockIdx.x * blockDim.x + threadIdx.x;
    int st = gridDim.x * blockDim.x;
    for (int k = i; k < NN; k += st) cnt[k] = 0;
    for (int k = i; k < NLIST; k += st) nodelist[k] = 0xFFFFFFFFu;
    if (i < 16) misc[i] = 0;
    if (i == 0) out[0] = reg_b[0];
}

__global__ void k_count(const int* __restrict__ ei, const int* __restrict__ nt,
                        int* cnt, int* __restrict__ rank, int* misc) {
    int i = blockIdx.x * blockDim.x + threadIdx.x;
    int st = gridDim.x * blockDim.x;
    for (int e = i; e < NE; e += st) {
        int d = ei[NE + e];
        rank[e] = atomicAdd(&cnt[d], 1);
    }
    int lane = threadIdx.x & 63;
    for (int n = i; n < NN; n += st) {
        int t = nt[n];
#pragma unroll
        for (int tt = 0; tt < 4; tt++) {
            unsigned long long m = __ballot(t == tt);
            if (t == tt && lane == (__ffsll((unsigned long long)m) - 1))
                atomicAdd(&misc[tt], (int)__popcll(m));
        }
    }
}

__global__ __launch_bounds__(256) void k_scan1(const int* cnt, int* off, int* bsum) {
    __shared__ int s[256];
    int tid = threadIdx.x;
    int i = blockIdx.x * 256 + tid;
    int v = (i < NN) ? cnt[i] : 0;
    s[tid] = v;
    __syncthreads();
    for (int o = 1; o < 256; o <<= 1) {
        int t = (tid >= o) ? s[tid - o] : 0;
        __syncthreads();
        s[tid] += t;
        __syncthreads();
    }
    if (i < NN) off[i] = s[tid] - v;
    if (tid == 255) bsum[blockIdx.x] = s[255];
}

__global__ __launch_bounds__(512) void k_scan2(int* bsum, int* misc) {
    __shared__ int s[512];
    int tid = threadIdx.x;
    int v = (tid < SCAN_B) ? bsum[tid] : 0;
    s[tid] = v;
    __syncthreads();
    for (int o = 1; o < 512; o <<= 1) {
        int t = (tid >= o) ? s[tid - o] : 0;
        __syncthreads();
        s[tid] += t;
        __syncthreads();
    }
    if (tid < SCAN_B) bsum[tid] = s[tid] - v;
    if (tid == 0) {
        int base = 0;
        for (int t = 0; t < 4; t++) { misc[4 + t] = base; base += (misc[t] + 31) & ~31; }
    }
}

__global__ __launch_bounds__(256) void k_scan3(const int* cnt, int* off,
                                               const int* bsum, float* inv_deg) {
    int i = blockIdx.x * 256 + threadIdx.x;
    if (i < NN) {
        off[i] += bsum[blockIdx.x];
        int c = cnt[i];
        inv_deg[i] = 1.0f / (float)(c > 0 ? c : 1);
    }
}

__global__ __launch_bounds__(256) void k_fill_e(const int* __restrict__ ei,
                                                const int* __restrict__ et,
                                                const int* __restrict__ off,
                                                const int* __restrict__ rank,
                                                unsigned* __restrict__ packed) {
    int i = blockIdx.x * blockDim.x + threadIdx.x;
    int st = gridDim.x * blockDim.x;
    for (int p = 0; p < FILL_PASSES; p++) {
        int lo = p * REGION;
        for (int e = i; e < NE; e += st) {
            int d = ei[NE + e];
            if ((unsigned)(d - lo) < (unsigned)REGION) {
                packed[off[d] + rank[e]] = (unsigned)ei[e] | ((unsigned)et[e] << 17);
            }
        }
    }
}

__global__ __launch_bounds__(256) void k_fill_n(const int* __restrict__ nt,
                                                int* misc, unsigned* nodelist) {
    int i = blockIdx.x * blockDim.x + threadIdx.x;
    int st = gridDim.x * blockDim.x;
    int lane = threadIdx.x & 63;
    int bases[4] = {misc[4], misc[5], misc[6], misc[7]};
    for (int n = i; n < NN; n += st) {
        int t = nt[n];
#pragma unroll
        for (int tt = 0; tt < 4; tt++) {
            unsigned long long m = __ballot(t == tt);
            if (t == tt) {
                int leader = __ffsll((unsigned long long)m) - 1;
                int base = 0;
                if (lane == leader) base = atomicAdd(&misc[8 + tt], (int)__popcll(m));
                base = __shfl(base, leader);
                int prefix = (int)__popcll(m & (((unsigned long long)1 << lane) - 1));
                nodelist[bases[tt] + base + prefix] = (unsigned)n | ((unsigned)tt << 17);
            }
        }
    }
}

// weights -> bf16 B-fragment order, hi + lo split (w = hi + lo, residual ~2^-18):
// flat ushort16 idx fields: j[2:0] lane[8:3] nt[11:9] kt[15:12] l[16]
// Wb*[idx] = W[l][kt*32+(lane>>4)*8+j][nt*16+(lane&15)]
__global__ void k_wcat(const float* rel_W, const float* lin_W,
                       ushort16* Wbh, ushort16* Wbl) {
    int i = blockIdx.x * blockDim.x + threadIdx.x;
    int st = gridDim.x * blockDim.x;
    for (int idx = i; idx < 2 * 512 * 128; idx += st) {
        int j = idx & 7;
        int lane = (idx >> 3) & 63;
        int ntile = (idx >> 9) & 7;
        int kt = (idx >> 12) & 15;
        int l = (idx >> 16) & 1;
        int k = kt * 32 + ((lane >> 4) * 8) + j;
        int n = ntile * 16 + (lane & 15);
        float v;
        if (k < 384) v = rel_W[((l * 3 + (k >> 7)) * HD + (k & 127)) * HD + n];
        else         v = lin_W[(l * HD + (k - 384)) * HD + n];
        ushort16 hi = f2bf(v);
        Wbh[idx] = hi;
        Wbl[idx] = f2bf(v - bf2f1(hi));
    }
}

// ---------------- encoder (bf16 output) ----------------

#define FMA16(A, v0, v1, v2, v3, w)                                       \
    A[0] += v0.x * w; A[1] += v0.y * w; A[2] += v0.z * w; A[3] += v0.w * w; \
    A[4] += v1.x * w; A[5] += v1.y * w; A[6] += v1.z * w; A[7] += v1.w * w; \
    A[8] += v2.x * w; A[9] += v2.y * w; A[10] += v2.z * w; A[11] += v2.w * w; \
    A[12] += v3.x * w; A[13] += v3.y * w; A[14] += v3.z * w; A[15] += v3.w * w;

__global__ __launch_bounds__(256) void k_enc(
        const unsigned* nodelist, const int* z, const float* sd, const float* df,
        const float* cond, const float* mult, const float* z_embed,
        const float* W1, const float* b1, const float* W2, const float* b2,
        ushort16* xout) {
    __shared__ float raw[32][20];
    __shared__ float h1[128][36];
    __shared__ unsigned ent[32];
    int tid = threadIdx.x;
    int base = blockIdx.x * 32;
    if (tid < 32) ent[tid] = nodelist[base + tid];
    __syncthreads();
    if (ent[0] == 0xFFFFFFFFu) return;
    int type = (int)(ent[0] >> 17);

    for (int idx = tid; idx < 32 * 20; idx += 256) {
        int nl = idx / 20, f = idx - nl * 20;
        unsigned e = ent[nl];
        float v = 0.f;
        if (e != 0xFFFFFFFFu) {
            int node = (int)(e & 0x1FFFF);
            if (f < 16)      v = z_embed[z[node] * 16 + f];
            else if (f == 16) v = sd[node];
            else if (f == 17) v = df[node];
            else if (f == 18) v = cond[node];
            else              v = mult[node];
        }
        raw[nl][f] = v;
    }
    __syncthreads();

    int j = tid & 127, n0 = (tid >> 7) * 16;
    const float* W1t = W1 + type * IND * HD;
    const float* W2t = W2 + type * HD * HD;

    float acc[16];
#pragma unroll
    for (int i = 0; i < 16; i++) acc[i] = 0.f;
    for (int k = 0; k < IND; k++) {
        float w = W1t[k * HD + j];
#pragma unroll
        for (int i = 0; i < 16; i++) acc[i] += raw[n0 + i][k] * w;
    }
    float bb = b1[type * HD + j];
#pragma unroll
    for (int i = 0; i < 16; i++) h1[j][n0 + i] = fmaxf(acc[i] + bb, 0.f);
    __syncthreads();

#pragma unroll
    for (int i = 0; i < 16; i++) acc[i] = 0.f;
    for (int k = 0; k < HD; k++) {
        float w = W2t[k * HD + j];
        const float4* hp = (const float4*)&h1[k][n0];
        float4 v0 = hp[0], v1 = hp[1], v2 = hp[2], v3 = hp[3];
        FMA16(acc, v0, v1, v2, v3, w)
    }
    float b2v = b2[type * HD + j];
#pragma unroll
    for (int i = 0; i < 16; i++) {
        unsigned e = ent[n0 + i];
        if (e != 0xFFFFFFFFu) {
            int node = (int)(e & 0x1FFFF);
            xout[node * HD + j] = f2bf(acc[i] + b2v);
        }
    }
}

// ---------------- fused layer: aggregate -> LDS bf16 A-tile -> MFMA -> LayerNorm ----------------

#define ACCSEL(r, v)                                   \
    a0.x += ((r) == 0) ? (v).x : 0.f;                  \
    a0.y += ((r) == 0) ? (v).y : 0.f;                  \
    a1.x += ((r) == 1) ? (v).x : 0.f;                  \
    a1.y += ((r) == 1) ? (v).y : 0.f;                  \
    a2.x += ((r) == 2) ? (v).x : 0.f;                  \
    a2.y += ((r) == 2) ? (v).y : 0.f;

__global__ __launch_bounds__(256) void k_fused(
        const ushort16* __restrict__ x, const unsigned* __restrict__ packed,
        const int* __restrict__ off, const int* __restrict__ cnt,
        const float* __restrict__ inv_deg,
        const ushort16* __restrict__ Wbh, const ushort16* __restrict__ Wbl,
        const float* __restrict__ lb, const float* __restrict__ g,
        const float* __restrict__ bta, ushort16* __restrict__ xout) {
    __shared__ uint32 Alds[32 * ASTRIDE];   // bf16 A-tile [32][520]; aliased as hlds [32][132] f32
    __shared__ float stat[32][2];
    int tid = threadIdx.x;
    int lane = tid & 63;
    int wv = tid >> 6;
    int nb = blockIdx.x * 32;

    const uint32* xw = (const uint32*)x;   // one uint (2 bf16) per lane, row stride 64

    // ---- phase A: aggregate, write bf16 panels to LDS ----
#pragma unroll
    for (int i = 0; i < 8; i++) {
        int node = nb + wv * 8 + i;
        int o = __builtin_amdgcn_readfirstlane(off[node]);
        int c = __builtin_amdgcn_readfirstlane(cnt[node]);
        float2 a0 = {0.f, 0.f}, a1 = {0.f, 0.f}, a2 = {0.f, 0.f};
        int e = 0;
        for (; e + 8 <= c; e += 8) {
            unsigned q0 = packed[o + e];
            unsigned q1 = packed[o + e + 1];
            unsigned q2 = packed[o + e + 2];
            unsigned q3 = packed[o + e + 3];
            unsigned q4 = packed[o + e + 4];
            unsigned q5 = packed[o + e + 5];
            unsigned q6 = packed[o + e + 6];
            unsigned q7 = packed[o + e + 7];
            float2 v0 = bf2f(xw[(size_t)(q0 & 0x1FFFF) * 64 + lane]);
            float2 v1 = bf2f(xw[(size_t)(q1 & 0x1FFFF) * 64 + lane]);
            float2 v2 = bf2f(xw[(size_t)(q2 & 0x1FFFF) * 64 + lane]);
            float2 v3 = bf2f(xw[(size_t)(q3 & 0x1FFFF) * 64 + lane]);
            float2 v4 = bf2f(xw[(size_t)(q4 & 0x1FFFF) * 64 + lane]);
            float2 v5 = bf2f(xw[(size_t)(q5 & 0x1FFFF) * 64 + lane]);
            float2 v6 = bf2f(xw[(size_t)(q6 & 0x1FFFF) * 64 + lane]);
            float2 v7 = bf2f(xw[(size_t)(q7 & 0x1FFFF) * 64 + lane]);
            int r0 = (int)(q0 >> 17), r1 = (int)(q1 >> 17);
            int r2 = (int)(q2 >> 17), r3 = (int)(q3 >> 17);
            int r4 = (int)(q4 >> 17), r5 = (int)(q5 >> 17);
            int r6 = (int)(q6 >> 17), r7 = (int)(q7 >> 17);
            ACCSEL(r0, v0) ACCSEL(r1, v1) ACCSEL(r2, v2) ACCSEL(r3, v3)
            ACCSEL(r4, v4) ACCSEL(r5, v5) ACCSEL(r6, v6) ACCSEL(r7, v7)
        }
        for (; e < c; e++) {
            unsigned q = packed[o + e];
            float2 v = bf2f(xw[(size_t)(q & 0x1FFFF) * 64 + lane]);
            int r = (int)(q >> 17);
            ACCSEL(r, v)
        }
        float id = inv_deg[node];
        int row = wv * 8 + i;
        uint32* ar = Alds + row * ASTRIDE;
        float2 s0 = {a0.x * id, a0.y * id};
        float2 s1 = {a1.x * id, a1.y * id};
        float2 s2 = {a2.x * id, a2.y * id};
        ar[lane]       = pack2bf(s0);
        ar[64 + lane]  = pack2bf(s1);
        ar[128 + lane] = pack2bf(s2);
        ar[192 + lane] = xw[(size_t)node * 64 + lane];
    }
    __syncthreads();

    // ---- phase B: MFMA GEMM (W = Whi + Wlo) ----
    f32x4 acc00 = {0.f, 0.f, 0.f, 0.f}, acc01 = acc00, acc10 = acc00, acc11 = acc00;
    int mrow0 = (lane & 15);
    int mrow1 = 16 + (lane & 15);
    int q4 = (lane >> 4) * 4;              // word offset of this lane's k-slice
    const bf16x8* wbh = (const bf16x8*)Wbh;
    const bf16x8* wbl = (const bf16x8*)Wbl;
    int nt0 = 2 * wv, nt1 = 2 * wv + 1;

#pragma unroll 4
    for (int kt = 0; kt < 16; kt++) {
        bf16x8 af0 = *(const bf16x8*)&Alds[mrow0 * ASTRIDE + kt * 16 + q4];
        bf16x8 af1 = *(const bf16x8*)&Alds[mrow1 * ASTRIDE + kt * 16 + q4];
        bf16x8 bh0 = wbh[(kt * 8 + nt0) * 64 + lane];
        bf16x8 bh1 = wbh[(kt * 8 + nt1) * 64 + lane];
        bf16x8 bl0 = wbl[(kt * 8 + nt0) * 64 + lane];
        bf16x8 bl1 = wbl[(kt * 8 + nt1) * 64 + lane];
        acc00 = __builtin_amdgcn_mfma_f32_16x16x32_bf16(af0, bh0, acc00, 0, 0, 0);
        acc01 = __builtin_amdgcn_mfma_f32_16x16x32_bf16(af0, bh1, acc01, 0, 0, 0);
        acc10 = __builtin_amdgcn_mfma_f32_16x16x32_bf16(af1, bh0, acc10, 0, 0, 0);
        acc11 = __builtin_amdgcn_mfma_f32_16x16x32_bf16(af1, bh1, acc11, 0, 0, 0);
        acc00 = __builtin_amdgcn_mfma_f32_16x16x32_bf16(af0, bl0, acc00, 0, 0, 0);
        acc01 = __builtin_amdgcn_mfma_f32_16x16x32_bf16(af0, bl1, acc01, 0, 0, 0);
        acc10 = __builtin_amdgcn_mfma_f32_16x16x32_bf16(af1, bl0, acc10, 0, 0, 0);
        acc11 = __builtin_amdgcn_mfma_f32_16x16x32_bf16(af1, bl1, acc11, 0, 0, 0);
    }
    __syncthreads();   // A-tile reads done; safe to alias as hlds

    // ---- bias + LayerNorm ----
    float* hlds = (float*)Alds;            // [32][132]
    int n0 = nt0 * 16 + (lane & 15);
    int n1 = n0 + 16;
    float bj0 = lb[n0], bj1 = lb[n1];
    int rbase = (lane >> 4) * 4;           // D row base within tile
#pragma unroll
    for (int r = 0; r < 4; r++) {
        hlds[(rbase + r) * 132 + n0]      = acc00[r] + bj0;
        hlds[(rbase + r) * 132 + n1]      = acc01[r] + bj1;
        hlds[(16 + rbase + r) * 132 + n0] = acc10[r] + bj0;
        hlds[(16 + rbase + r) * 132 + n1] = acc11[r] + bj1;
    }
    __syncthreads();

    {
        int node = tid >> 3, l8 = tid & 7;
        float s = 0.f, ss = 0.f;
#pragma unroll
        for (int i = 0; i < 16; i++) {
            float v = hlds[node * 132 + l8 + 8 * i];
            s += v; ss += v * v;
        }
        for (int d = 4; d >= 1; d >>= 1) {
            s += __shfl_down(s, d, 8);
            ss += __shfl_down(ss, d, 8);
        }
        if (l8 == 0) {
            float mu = s * (1.f / 128.f);
            float var = ss * (1.f / 128.f) - mu * mu;
            stat[node][0] = mu;
            stat[node][1] = rsqrtf(var + LNEPS);
        }
    }
    __syncthreads();

    float g0 = g[n0], g1 = g[n1], bt0 = bta[n0], bt1 = bta[n1];
#pragma unroll
    for (int r = 0; r < 4; r++) {
        int m0 = rbase + r, m1 = 16 + rbase + r;
        float mu0 = stat[m0][0], rs0 = stat[m0][1];
        float mu1 = stat[m1][0], rs1 = stat[m1][1];
        xout[(size_t)(nb + m0) * HD + n0] = f2bf((acc00[r] + bj0 - mu0) * rs0 * g0 + bt0);
        xout[(size_t)(nb + m0) * HD + n1] = f2bf((acc01[r] + bj1 - mu0) * rs0 * g1 + bt1);
        xout[(size_t)(nb + m1) * HD + n0] = f2bf((acc10[r] + bj0 - mu1) * rs1 * g0 + bt0);
        xout[(size_t)(nb + m1) * HD + n1] = f2bf((acc11[r] + bj1 - mu1) * rs1 * g1 + bt1);
    }
}

// ---------------- pooling + regressor ----------------

__global__ __launch_bounds__(256) void k_pool(const ushort16* __restrict__ x,
                                              const float* regW, float* out) {
    int tid = threadIdx.x;
    int j = tid & 127;
    float s = 0.f;
    int node = blockIdx.x * 2 + (tid >> 7);
    for (; node < NN; node += gridDim.x * 2) {
        uint32 u = (uint32)x[(size_t)node * HD + j];
        s += __uint_as_float(u << 16);
    }
    s *= regW[j];
    __shared__ float red[4];
    for (int d = 32; d >= 1; d >>= 1) s += __shfl_down(s, d, 64);
    if ((tid & 63) == 0) red[tid >> 6] = s;
    __syncthreads();
    if (tid == 0) {
        float t = red[0] + red[1] + red[2] + red[3];
        atomicAdd(out, t * (1.0f / (float)NN));
    }
}

// ---------------- launcher ----------------

extern "C" void kernel_launch(void* const* d_in, const int* in_sizes, int n_in,
                              void* d_out, int out_size, void* d_ws, size_t ws_size,
                              hipStream_t stream) {
    const int*   z       = (const int*)d_in[0];
    const float* sd      = (const float*)d_in[1];
    const float* df      = (const float*)d_in[2];
    const float* cond    = (const float*)d_in[3];
    const float* mult    = (const float*)d_in[4];
    const int*   nt      = (const int*)d_in[5];
    const int*   ei      = (const int*)d_in[6];
    const int*   et      = (const int*)d_in[7];
    const float* z_embed = (const float*)d_in[8];
    const float* enc_W1  = (const float*)d_in[9];
    const float* enc_b1  = (const float*)d_in[10];
    const float* enc_W2  = (const float*)d_in[11];
    const float* enc_b2  = (const float*)d_in[12];
    const float* lin_W   = (const float*)d_in[13];
    const float* lin_b   = (const float*)d_in[14];
    const float* rel_W   = (const float*)d_in[15];
    const float* ln_g    = (const float*)d_in[16];
    const float* ln_b    = (const float*)d_in[17];
    const float* reg_W   = (const float*)d_in[18];
    const float* reg_b   = (const float*)d_in[19];
    float* out = (float*)d_out;

    char* p = (char*)d_ws;
    int* cnt        = (int*)p;      p += (size_t)NN * 4;
    int* off        = (int*)p;      p += (size_t)NN * 4;
    int* rank       = (int*)p;      p += (size_t)NE * 4;
    int* misc       = (int*)p;      p += 16 * 4;
    int* bsum       = (int*)p;      p += 512 * 4;
    unsigned* packed   = (unsigned*)p; p += (size_t)NE * 4;
    unsigned* nodelist = (unsigned*)p; p += (size_t)NLIST * 4;
    float* inv_deg  = (float*)p;    p += (size_t)NN * 4;
    ushort16* Wbh   = (ushort16*)p; p += (size_t)2 * 512 * 128 * 2;
    ushort16* Wbl   = (ushort16*)p; p += (size_t)2 * 512 * 128 * 2;
    ushort16* x0    = (ushort16*)p; p += (size_t)NN * HD * 2;
    ushort16* x1    = (ushort16*)p; p += (size_t)NN * HD * 2;

    k_init<<<400, 256, 0, stream>>>(cnt, misc, nodelist, out, reg_b);
    k_count<<<2048, 256, 0, stream>>>(ei, nt, cnt, rank, misc);
    k_scan1<<<SCAN_B, 256, 0, stream>>>(cnt, off, bsum);
    k_scan2<<<1, 512, 0, stream>>>(bsum, misc);
    k_scan3<<<SCAN_B, 256, 0, stream>>>(cnt, off, bsum, inv_deg);
    k_fill_e<<<2048, 256, 0, stream>>>(ei, et, off, rank, packed);
    k_fill_n<<<400, 256, 0, stream>>>(nt, misc, nodelist);
    k_wcat<<<512, 256, 0, stream>>>(rel_W, lin_W, Wbh, Wbl);
    k_enc<<<3129, 256, 0, stream>>>(nodelist, z, sd, df, cond, mult, z_embed,
                                    enc_W1, enc_b1, enc_W2, enc_b2, x0);

    ushort16* xin = x0; ushort16* xo = x1;
    for (int l = 0; l < 2; l++) {
        k_fused<<<NN / 32, 256, 0, stream>>>(xin, packed, off, cnt, inv_deg,
                                             Wbh + (size_t)l * 512 * 128,
                                             Wbl + (size_t)l * 512 * 128,
                                             lin_b + l * HD, ln_g + l * HD, ln_b + l * HD,
                                             xo);
        ushort16* t = xin; xin = xo; xo = t;
    }
    k_pool<<<256, 256, 0, stream>>>(xin, reg_W, out);
}